// Round 10
// baseline (231.204 us; speedup 1.0000x reference)
//
#include <hip/hip_runtime.h>
#include <math.h>

#define NB 1024

// problem dims
#define TT 1024
#define DD 512
#define HH 8
#define DH 64
#define TB 4

// ws float offsets
#define QP_OFF       0u
#define KP_OFF       1048576u
#define VP_OFF       2097152u
#define DWQ_PRE_OFF  3145728u
#define DWK_PRE_OFF  3211264u
#define GQ_PRE_OFF   3276800u
#define GK_PRE_OFF   3293184u
#define DWQ_POST_OFF 3309568u
#define DWK_POST_OFF 3375104u
#define GQ_POST_OFF  3440640u
#define GK_POST_OFF  3457024u

// out float offsets
#define OUT_OFF   0u
#define UNC_OFF   1048576u
#define PROBS_OFF 17825792u
#define POST_OFF  34603008u

// Relaxed barrier: orders LDS only (lgkmcnt), leaves global-store queue
// (vmcnt) draining in the background. Used ONLY where the preceding phase's
// global stores are to never-re-read output regions.
__device__ __forceinline__ void bar_lds()
{
    asm volatile("s_waitcnt lgkmcnt(0)" ::: "memory");
    __builtin_amdgcn_s_barrier();
    __builtin_amdgcn_sched_barrier(0);
}

// ---------------------------------------------------------------------------
// K_prep: fused proj + small, one launch.
//   units [0,384):    proj 128x64 tile (FROZEN from R8): z = u>>7,
//                     bx = (u&127)&15, by = (u&127)>>4. kp stored TRANSPOSED.
//   units [384,1408): small: rowblk = (u-384)&255, combo = (u-384)>>8.
// R10 small-path rework:
//   - p1 chunk-staged in LDS (8 chunks of [64][32]): 512 global loads/thread
//     -> 16 float4 staging loads + LDS reads (bank-conflict-free).
//   - gate path all-lanes: 128-d partials per (r, c&7, seg=c>>3), folded via
//     shfl_xor(8,16); replaces the 75%-idle `if (c<8)` 512-dot.
// LDS union: proj 25600 B, small 29696 B (qs 16K + p1s 8K + u1s 1K + p2s 4K).
// ---------------------------------------------------------------------------
__global__ __launch_bounds__(256) void k_prep(
    const float* __restrict__ q, const float* __restrict__ k, const float* __restrict__ v,
    const float* __restrict__ wq, const float* __restrict__ bq,
    const float* __restrict__ wk, const float* __restrict__ bk,
    const float* __restrict__ wv, const float* __restrict__ bv,
    const float* __restrict__ pq1, const float* __restrict__ pq2,
    const float* __restrict__ pk1, const float* __restrict__ pk2,
    const float* __restrict__ pqg, const float* __restrict__ pkg,
    const float* __restrict__ oq1, const float* __restrict__ oq2,
    const float* __restrict__ ok1, const float* __restrict__ ok2,
    const float* __restrict__ oqg, const float* __restrict__ okg,
    float* __restrict__ ws)
{
    __shared__ __align__(16) float smem[7424];   // 29696 B union

    const int u = blockIdx.x;
    const int tid = threadIdx.x;

    if (u < 384) {
        // ================= proj path: 128x64 tile (FROZEN) =================
        float (*As)[132] = reinterpret_cast<float (*)[132]>(smem);         // [32][132]
        float (*Wt)[68]  = reinterpret_cast<float (*)[68]>(smem + 4224);   // [32][68]

        const int z = u >> 7;
        const int rest = u & 127;
        const int bx = rest & 15;
        const int by = rest >> 4;

        const float* A  = (z == 0) ? q  : (z == 1) ? k  : v;
        const float* W  = (z == 0) ? wq : (z == 1) ? wk : wv;
        const float* bs = (z == 0) ? bq : (z == 1) ? bk : bv;
        float* C = ws + (unsigned)z * 1048576u;

        const int tx = tid & 15, ty = tid >> 4;
        const int row0 = bx * 128;
        const int col0 = by * 64;

        float4 acc[8];
        #pragma unroll
        for (int i = 0; i < 8; ++i) acc[i] = make_float4(0.f, 0.f, 0.f, 0.f);

        for (int k0 = 0; k0 < DD; k0 += 32) {
            #pragma unroll
            for (int p = 0; p < 4; ++p) {
                int qi = tid + p * 256;            // 0..1023 quad index
                int row = qi >> 3;                 // 0..127
                int kk4 = (qi & 7) << 2;           // 0..28
                float4 a = *(const float4*)&A[(size_t)(row0 + row) * DD + k0 + kk4];
                As[kk4 + 0][row] = a.x;
                As[kk4 + 1][row] = a.y;
                As[kk4 + 2][row] = a.z;
                As[kk4 + 3][row] = a.w;
            }
            #pragma unroll
            for (int p = 0; p < 2; ++p) {
                int qi = tid + p * 256;
                int kk = qi >> 4;                  // 0..31
                int c4 = (qi & 15) << 2;           // 0..60
                *(float4*)&Wt[kk][c4] = *(const float4*)&W[(size_t)(k0 + kk) * DD + col0 + c4];
            }
            __syncthreads();
            #pragma unroll
            for (int kk = 0; kk < 32; ++kk) {
                float4 a0 = *(const float4*)&As[kk][ty << 3];
                float4 a1 = *(const float4*)&As[kk][(ty << 3) + 4];
                float4 w  = *(const float4*)&Wt[kk][tx << 2];
                acc[0].x += a0.x*w.x; acc[0].y += a0.x*w.y; acc[0].z += a0.x*w.z; acc[0].w += a0.x*w.w;
                acc[1].x += a0.y*w.x; acc[1].y += a0.y*w.y; acc[1].z += a0.y*w.z; acc[1].w += a0.y*w.w;
                acc[2].x += a0.z*w.x; acc[2].y += a0.z*w.y; acc[2].z += a0.z*w.z; acc[2].w += a0.z*w.w;
                acc[3].x += a0.w*w.x; acc[3].y += a0.w*w.y; acc[3].z += a0.w*w.z; acc[3].w += a0.w*w.w;
                acc[4].x += a1.x*w.x; acc[4].y += a1.x*w.y; acc[4].z += a1.x*w.z; acc[4].w += a1.x*w.w;
                acc[5].x += a1.y*w.x; acc[5].y += a1.y*w.y; acc[5].z += a1.y*w.z; acc[5].w += a1.y*w.w;
                acc[6].x += a1.z*w.x; acc[6].y += a1.z*w.y; acc[6].z += a1.z*w.z; acc[6].w += a1.z*w.w;
                acc[7].x += a1.w*w.x; acc[7].y += a1.w*w.y; acc[7].z += a1.w*w.z; acc[7].w += a1.w*w.w;
            }
            __syncthreads();
        }
        float4 bias4 = *(const float4*)&bs[col0 + (tx << 2)];

        if (z == 1) {
            #pragma unroll
            for (int i = 0; i < 8; ++i) {
                const int row  = row0 + (ty << 3) + i;       // 0..2047
                const int bi   = row >> 10;
                const int s_in = row & 1023;
                const int h    = s_in >> 7;
                float va[4] = { acc[i].x + bias4.x, acc[i].y + bias4.y,
                                acc[i].z + bias4.z, acc[i].w + bias4.w };
                #pragma unroll
                for (int j = 0; j < 4; ++j) {
                    const int col   = col0 + (tx << 2) + j;
                    const int s_att = ((s_in & 127) << 3) | (col >> 6);
                    const int dh    = col & 63;
                    C[(size_t)bi * 524288u + (size_t)(((h << 6) + dh) << 10) + s_att] = va[j];
                }
            }
        } else {
            #pragma unroll
            for (int i = 0; i < 8; ++i) {
                float4 r;
                r.x = acc[i].x + bias4.x; r.y = acc[i].y + bias4.y;
                r.z = acc[i].z + bias4.z; r.w = acc[i].w + bias4.w;
                *(float4*)&C[(size_t)(row0 + (ty << 3) + i) * DD + col0 + (tx << 2)] = r;
            }
        }
    } else {
        // ================= small path (R10 rework) =================
        float (*qs)[512]  = reinterpret_cast<float (*)[512]>(smem);        // [8][512]   16 KB
        float (*p1s)[32]  = reinterpret_cast<float (*)[32]>(smem + 4096);  // [64][32]    8 KB
        float (*u1s)[32]  = reinterpret_cast<float (*)[32]>(smem + 6144);  // [8][32]     1 KB
        float* p2s = smem + 6400;                                          // [1024]      4 KB

        const int u2 = u - 384;
        const int rowblk = u2 & 255;
        const int combo = u2 >> 8;

        const float* A; const float* p1; const float* p2; const float* pg;
        float* dwout; float* gout;
        if (combo == 0)      { A = q; p1 = pq1; p2 = pq2; pg = pqg; dwout = ws + DWQ_PRE_OFF;  gout = ws + GQ_PRE_OFF;  }
        else if (combo == 1) { A = k; p1 = pk1; p2 = pk2; pg = pkg; dwout = ws + DWK_PRE_OFF;  gout = ws + GK_PRE_OFF;  }
        else if (combo == 2) { A = q; p1 = oq1; p2 = oq2; pg = oqg; dwout = ws + DWQ_POST_OFF; gout = ws + GQ_POST_OFF; }
        else                 { A = k; p1 = ok1; p2 = ok2; pg = okg; dwout = ws + DWK_POST_OFF; gout = ws + GK_POST_OFF; }

        const int row0 = rowblk * 8;

        for (int i = tid; i < 8 * 512; i += 256)
            qs[i >> 9][i & 511] = A[(size_t)(row0 + (i >> 9)) * 512 + (i & 511)];
        for (int i = tid; i < 1024; i += 256) p2s[i] = p2[i];

        const int r = tid >> 5, c = tid & 31;

        // ---- u1 = gelu(qs @ p1), p1 staged in 8 LDS chunks of [64][32] ----
        float acc = 0.f;
        for (int ch = 0; ch < 8; ++ch) {
            __syncthreads();                   // ch=0: covers qs/p2s staging too
            // stage 2048 floats = 512 float4; 2 float4 per thread, coalesced
            {
                const float4* src = (const float4*)(p1 + (ch << 11));
                float4* dst = (float4*)&p1s[0][0];
                dst[tid]       = src[tid];
                dst[tid + 256] = src[tid + 256];
            }
            __syncthreads();
            const float* qrow = &qs[r][ch << 6];
            #pragma unroll
            for (int d = 0; d < 64; ++d)
                acc += qrow[d] * p1s[d][c];    // qs: broadcast; p1s: bank c
        }
        float uu = 0.5f * acc * (1.f + erff(acc * 0.70710678118f));   // exact gelu
        u1s[r][c] = uu;
        __syncthreads();

        float dw = 0.f;
        #pragma unroll
        for (int cc = 0; cc < 32; ++cc) dw += u1s[r][cc] * p2s[cc * 32 + c];
        dwout[(size_t)(row0 + r) * 32 + c] = dw;

        // ---- g = tanh(qs @ pg), all lanes: (r, cg=c&7) over segment c>>3 ----
        {
            const int cg = c & 7, seg = c >> 3;       // 4 segments x 128 d
            const float* qrow = &qs[r][seg << 7];
            const float* pgp = pg + ((seg << 7) << 3) + cg;
            float gp = 0.f;
            #pragma unroll 4
            for (int d = 0; d < 128; ++d)
                gp += qrow[d] * pgp[d << 3];
            gp += __shfl_xor(gp, 8);                  // fold seg^1
            gp += __shfl_xor(gp, 16);                 // fold seg^2
            if (seg == 0)
                gout[(size_t)(row0 + r) * 8 + cg] = tanhf(gp);
        }
    }
}

// ---------------------------------------------------------------------------
// K2: fused logits -> uncomposed -> pre -> probs -> post -> out
// FROZEN from R9 (165.5 us, VGPR 60, no spill; bar_lds store-drain overlap).
// CLOSED AXES (do not retry):
//  - TB=2 pure (R7): dur 241 us. TB=4 wins.
//  - wmaxs fold / reshaped row_stats (R2-R5): ~1-2 GB scratch spill.
//  - launch_bounds 2nd arg must stay 4 (64-VGPR budget; 8 caps at 32).
//  - P3/P5 must stay in LOOP form (straight-line ss=tid spills, R3/R4).
// ---------------------------------------------------------------------------
__device__ __forceinline__ void row_stats(const float* Lb, float* rowm, float* rowsum, int tid)
{
    const int g = tid >> 5, l = tid & 31;          // 32 groups x 32 lanes
    const float* row = Lb + (g << 10);
    float m = -1e30f;
    #pragma unroll
    for (int i = 0; i < 8; ++i) {
        float4 v = *(const float4*)&row[(i << 7) + (l << 2)];
        m = fmaxf(m, fmaxf(fmaxf(v.x, v.y), fmaxf(v.z, v.w)));
    }
    #pragma unroll
    for (int o = 16; o >= 1; o >>= 1) m = fmaxf(m, __shfl_xor(m, o));
    float sm = 0.f;
    #pragma unroll
    for (int i = 0; i < 8; ++i) {
        float4 v = *(const float4*)&row[(i << 7) + (l << 2)];
        sm += __expf(v.x - m) + __expf(v.y - m) + __expf(v.z - m) + __expf(v.w - m);
    }
    #pragma unroll
    for (int o = 16; o >= 1; o >>= 1) sm += __shfl_xor(sm, o);
    if (l == 0) { rowm[g] = m; rowsum[g] = 1.0f / sm; }
}

__global__ __launch_bounds__(1024, 4) void k_fused(
    const float* __restrict__ ws, float* __restrict__ dout)
{
    __shared__ float Lb[TB * HH * 1024];     // 128 KB: logits->pre->probs->post
    __shared__ float qv[HH * TB * DH];       // 8 KB: q head-rows [h][t][d]; reused as P6 partials
    __shared__ float dqp[TB][32];
    __shared__ float dqo[TB][32];
    __shared__ float gqp_s[TB][8];
    __shared__ float gqo_s[TB][8];
    __shared__ float rowm[32];
    __shared__ float rowsum[32];             // holds RECIPROCAL of softmax denom

    const int tid = threadIdx.x;
    const int bid = blockIdx.x;
    const int b = bid & 1;                   // batch per XCD parity (L2 locality)
    const int t0 = (bid >> 1) * TB;

    const float* qp = ws + QP_OFF + b * 524288u;
    const float* kp = ws + KP_OFF + b * 524288u;   // TRANSPOSED: [h][dh][s]
    const float* vp = ws + VP_OFF + b * 524288u;
    const float* dwk_pre  = ws + DWK_PRE_OFF  + b * 32768u;
    const float* gk_pre   = ws + GK_PRE_OFF   + b * 8192u;
    const float* dwk_post = ws + DWK_POST_OFF + b * 32768u;
    const float* gk_post  = ws + GK_POST_OFF  + b * 8192u;
    const float* dwq_pre  = ws + DWQ_PRE_OFF  + b * 32768u;
    const float* gq_pre   = ws + GQ_PRE_OFF   + b * 8192u;
    const float* dwq_post = ws + DWQ_POST_OFF + b * 32768u;
    const float* gq_post  = ws + GQ_POST_OFF  + b * 8192u;

    // ---- P0: load q rows + per-t params ----
    for (int i = tid; i < HH * TB * DH; i += NB) {
        int hh = i >> 8, t = (i >> 6) & 3, d = i & 63;
        qv[i] = qp[(size_t)((hh << 10) + t0 + t) * 64 + d];
    }
    if (tid < TB * 32) {
        int t = tid >> 5, j = tid & 31;
        dqp[t][j] = dwq_pre[(t0 + t) * 32 + j];
        dqo[t][j] = dwq_post[(t0 + t) * 32 + j];
    }
    if (tid < TB * 8) {
        int t = tid >> 3, h2 = tid & 7;
        gqp_s[t][h2] = gq_pre[(t0 + t) * 8 + h2];
        gqo_s[t][h2] = gq_post[(t0 + t) * 8 + h2];
    }
    __syncthreads();

    // ---- P1: logits = (qh . kh)/8 ; wave -> (head, s-half); kp is [h][d][s]
    //      lane covers 4 consecutive s (x2 chunks of 256) -> fully coalesced ----
    {
        const int w = tid >> 6, lane = tid & 63;
        const int h = w & 7;
        const int sb = (w >> 3) << 9;                 // 0 or 512
        const float* kbase = kp + ((size_t)(h << 6) << 10) + sb + (lane << 2);

        float4 acc0[TB], acc1[TB];
        #pragma unroll
        for (int t = 0; t < TB; ++t) {
            acc0[t] = make_float4(0.f, 0.f, 0.f, 0.f);
            acc1[t] = make_float4(0.f, 0.f, 0.f, 0.f);
        }
        for (int d0 = 0; d0 < 64; d0 += 4) {
            float4 qq[TB];
            #pragma unroll
            for (int t = 0; t < TB; ++t)
                qq[t] = *(const float4*)&qv[((h << 2 | t) << 6) + d0];
            #pragma unroll
            for (int dd = 0; dd < 4; ++dd) {
                const float* kr = kbase + ((size_t)(d0 + dd) << 10);
                float4 k0 = *(const float4*)kr;          // s = sb + lane*4
                float4 k1 = *(const float4*)(kr + 256);  // s = sb + 256 + lane*4
                #pragma unroll
                for (int t = 0; t < TB; ++t) {
                    float qd = (dd == 0) ? qq[t].x : (dd == 1) ? qq[t].y
                             : (dd == 2) ? qq[t].z : qq[t].w;
                    acc0[t].x += qd * k0.x; acc0[t].y += qd * k0.y;
                    acc0[t].z += qd * k0.z; acc0[t].w += qd * k0.w;
                    acc1[t].x += qd * k1.x; acc1[t].y += qd * k1.y;
                    acc1[t].z += qd * k1.z; acc1[t].w += qd * k1.w;
                }
            }
        }
        #pragma unroll
        for (int t = 0; t < TB; ++t) {
            float4 r0, r1;
            r0.x = acc0[t].x * 0.125f; r0.y = acc0[t].y * 0.125f;
            r0.z = acc0[t].z * 0.125f; r0.w = acc0[t].w * 0.125f;
            r1.x = acc1[t].x * 0.125f; r1.y = acc1[t].y * 0.125f;
            r1.z = acc1[t].z * 0.125f; r1.w = acc1[t].w * 0.125f;
            *(float4*)&Lb[((t << 3 | h) << 10) + sb + (lane << 2)] = r0;
            *(float4*)&Lb[((t << 3 | h) << 10) + sb + 256 + (lane << 2)] = r1;
        }
    }
    __syncthreads();

    // ---- P2: row stats of logits ----
    row_stats(Lb, rowm, rowsum, tid);
    __syncthreads();

    // ---- P3: write uncomposed; pre-compose in place ----
    for (int ss = tid; ss < 1024; ss += NB) {
        float kd[32], gk8[8];
        {
            const float4* p = (const float4*)&dwk_pre[ss << 5];
            #pragma unroll
            for (int j = 0; j < 8; ++j) *(float4*)&kd[j << 2] = p[j];
            const float4* g = (const float4*)&gk_pre[ss << 3];
            *(float4*)&gk8[0] = g[0];
            *(float4*)&gk8[4] = g[1];
        }
        #pragma unroll
        for (int t = 0; t < TB; ++t) {
            float L[8];
            #pragma unroll
            for (int h = 0; h < 8; ++h) L[h] = Lb[((t << 3 | h) << 10) + ss];
            #pragma unroll
            for (int h = 0; h < 8; ++h) {
                int r = (t << 3) | h;
                float e = __expf(L[h] - rowm[r]) * rowsum[r];
                __builtin_nontemporal_store(e,
                    &dout[UNC_OFF + (unsigned)(((b << 3 | h) << 10) + t0 + t) * 1024u + ss]);
            }
            float hq0 = 0.f, hq1 = 0.f, hk0 = 0.f, hk1 = 0.f;
            #pragma unroll
            for (int h = 0; h < 8; ++h) {
                hq0 += L[h] * dqp[t][h];
                hq1 += L[h] * dqp[t][8 + h];
                hk0 += L[h] * kd[h];
                hk1 += L[h] * kd[8 + h];
            }
            #pragma unroll
            for (int h = 0; h < 8; ++h) {
                float pre = L[h]
                          + hq0 * dqp[t][16 + h] + hq1 * dqp[t][24 + h]
                          + hk0 * kd[16 + h]     + hk1 * kd[24 + h]
                          + L[h] * gqp_s[t][h]   + L[h] * gk8[h];
                Lb[((t << 3 | h) << 10) + ss] = pre;
            }
        }
    }
    bar_lds();   // unc stores keep draining under P4

    // ---- P4: row stats of pre ----
    row_stats(Lb, rowm, rowsum, tid);
    __syncthreads();

    // ---- P5: write probs; post-compose in place; write post ----
    for (int ss = tid; ss < 1024; ss += NB) {
        float kd[32], gk8[8];
        {
            const float4* p = (const float4*)&dwk_post[ss << 5];
            #pragma unroll
            for (int j = 0; j < 8; ++j) *(float4*)&kd[j << 2] = p[j];
            const float4* g = (const float4*)&gk_post[ss << 3];
            *(float4*)&gk8[0] = g[0];
            *(float4*)&gk8[4] = g[1];
        }
        #pragma unroll
        for (int t = 0; t < TB; ++t) {
            float P[8];
            #pragma unroll
            for (int h = 0; h < 8; ++h) {
                int r = (t << 3) | h;
                P[h] = __expf(Lb[((t << 3 | h) << 10) + ss] - rowm[r]) * rowsum[r];
                __builtin_nontemporal_store(P[h],
                    &dout[PROBS_OFF + (unsigned)(((b << 3 | h) << 10) + t0 + t) * 1024u + ss]);
            }
            float hq0 = 0.f, hq1 = 0.f, hk0 = 0.f, hk1 = 0.f;
            #pragma unroll
            for (int h = 0; h < 8; ++h) {
                hq0 += P[h] * dqo[t][h];
                hq1 += P[h] * dqo[t][8 + h];
                hk0 += P[h] * kd[h];
                hk1 += P[h] * kd[8 + h];
            }
            #pragma unroll
            for (int h = 0; h < 8; ++h) {
                float pst = P[h]
                          + hq0 * dqo[t][16 + h] + hq1 * dqo[t][24 + h]
                          + hk0 * kd[16 + h]     + hk1 * kd[24 + h]
                          + P[h] * gqo_s[t][h]   + P[h] * gk8[h];
                Lb[((t << 3 | h) << 10) + ss] = pst;
                __builtin_nontemporal_store(pst,
                    &dout[POST_OFF + (unsigned)(((b << 3 | h) << 10) + t0 + t) * 1024u + ss]);
            }
        }
    }
    bar_lds();   // probs/post stores keep draining under P6

    // ---- P6: out = post @ v ; wave -> (head, s-half); float4 LDS reads ----
    {
        const int w = tid >> 6, lane = tid & 63;
        const int h = w & 7;
        const int shalf = w >> 3;                 // 0/1: s-half
        const int dq = lane & 15, sq = lane >> 4; // dq: out col quad, sq: s sub-quad
        float4 acc[TB];
        #pragma unroll
        for (int t = 0; t < TB; ++t) acc[t] = make_float4(0.f, 0.f, 0.f, 0.f);

        const int sbase = (shalf << 9) + (sq << 2);
        #pragma unroll 2
        for (int si = 0; si < 32; ++si) {
            const int s0 = sbase + (si << 4);
            float4 p4[TB];
            #pragma unroll
            for (int t = 0; t < TB; ++t)
                p4[t] = *(const float4*)&Lb[((t << 3 | h) << 10) + s0];
            #pragma unroll
            for (int j = 0; j < 4; ++j) {
                float4 vv = *(const float4*)&vp[((size_t)((h << 10) + s0 + j) << 6) + (dq << 2)];
                #pragma unroll
                for (int t = 0; t < TB; ++t) {
                    float pc = (j == 0) ? p4[t].x : (j == 1) ? p4[t].y
                             : (j == 2) ? p4[t].z : p4[t].w;
                    acc[t].x += pc * vv.x; acc[t].y += pc * vv.y;
                    acc[t].z += pc * vv.z; acc[t].w += pc * vv.w;
                }
            }
        }
        #pragma unroll
        for (int t = 0; t < TB; ++t) {
            #pragma unroll
            for (int o = 16; o <= 32; o <<= 1) {
                acc[t].x += __shfl_xor(acc[t].x, o);
                acc[t].y += __shfl_xor(acc[t].y, o);
                acc[t].z += __shfl_xor(acc[t].z, o);
                acc[t].w += __shfl_xor(acc[t].w, o);
            }
        }
        // cross-wave combine of the two s-halves via qv (dead after P1)
        if (shalf == 1 && sq == 0) {
            #pragma unroll
            for (int t = 0; t < TB; ++t)
                *(float4*)&qv[((h << 2 | t) << 6) + (dq << 2)] = acc[t];
        }
        bar_lds();   // only qv (LDS) ordering needed here
        if (shalf == 0 && sq == 0) {
            #pragma unroll
            for (int t = 0; t < TB; ++t) {
                float4 pr = *(const float4*)&qv[((h << 2 | t) << 6) + (dq << 2)];
                float4 r;
                r.x = acc[t].x + pr.x; r.y = acc[t].y + pr.y;
                r.z = acc[t].z + pr.z; r.w = acc[t].w + pr.w;
                *(float4*)&dout[OUT_OFF + (unsigned)((b << 10) + t0 + t) * 512u + (h << 6) + (dq << 2)] = r;
            }
        }
    }
}

// ---------------------------------------------------------------------------
extern "C" void kernel_launch(void* const* d_in, const int* in_sizes, int n_in,
                              void* d_out, int out_size, void* d_ws, size_t ws_size,
                              hipStream_t stream) {
    (void)in_sizes; (void)n_in; (void)out_size; (void)ws_size;
    const float* query = (const float*)d_in[0];
    const float* key   = (const float*)d_in[1];
    const float* value = (const float*)d_in[2];
    const float* wq = (const float*)d_in[3];
    const float* bq = (const float*)d_in[4];
    const float* wk = (const float*)d_in[5];
    const float* bk = (const float*)d_in[6];
    const float* wv = (const float*)d_in[7];
    const float* bv = (const float*)d_in[8];
    const float* pre_q1 = (const float*)d_in[9];
    const float* pre_q2 = (const float*)d_in[10];
    const float* pre_k1 = (const float*)d_in[11];
    const float* pre_k2 = (const float*)d_in[12];
    const float* pre_qg = (const float*)d_in[13];
    const float* pre_kg = (const float*)d_in[14];
    const float* post_q1 = (const float*)d_in[15];
    const float* post_q2 = (const float*)d_in[16];
    const float* post_k1 = (const float*)d_in[17];
    const float* post_k2 = (const float*)d_in[18];
    const float* post_qg = (const float*)d_in[19];
    const float* post_kg = (const float*)d_in[20];

    float* ws = (float*)d_ws;
    float* out = (float*)d_out;

    k_prep<<<1408, 256, 0, stream>>>(query, key, value, wq, bq, wk, bk, wv, bv,
        pre_q1, pre_q2, pre_k1, pre_k2, pre_qg, pre_kg,
        post_q1, post_q2, post_k1, post_k2, post_qg, post_kg, ws);
    k_fused<<<512, NB, 0, stream>>>(ws, out);
}

// Round 11
// 219.293 us; speedup vs baseline: 1.0543x; 1.0543x over previous
//
#include <hip/hip_runtime.h>
#include <math.h>

#define NB 1024

// problem dims
#define TT 1024
#define DD 512
#define HH 8
#define DH 64
#define TB 4

// ws float offsets
#define QP_OFF       0u
#define KP_OFF       1048576u
#define VP_OFF       2097152u
#define DWQ_PRE_OFF  3145728u
#define DWK_PRE_OFF  3211264u
#define GQ_PRE_OFF   3276800u
#define GK_PRE_OFF   3293184u
#define DWQ_POST_OFF 3309568u
#define DWK_POST_OFF 3375104u
#define GQ_POST_OFF  3440640u
#define GK_POST_OFF  3457024u

// out float offsets
#define OUT_OFF   0u
#define UNC_OFF   1048576u
#define PROBS_OFF 17825792u
#define POST_OFF  34603008u

// Relaxed barrier: orders LDS only (lgkmcnt), leaves global-store queue
// (vmcnt) draining in the background. Used ONLY where the preceding phase's
// global stores are to never-re-read output regions (post-P3, post-P5,
// mid-P6). __syncthreads() would force s_waitcnt vmcnt(0) first — a full
// HBM store drain with all 16 waves parked. [R9: +4.6 us]
__device__ __forceinline__ void bar_lds()
{
    asm volatile("s_waitcnt lgkmcnt(0)" ::: "memory");
    __builtin_amdgcn_s_barrier();
    __builtin_amdgcn_sched_barrier(0);
}

// ---------------------------------------------------------------------------
// K_prep: fused proj + small, one launch. FROZEN at R9 state.
//   units [0,384):    proj 128x64 tile: z = u>>7 (0=q,1=k,2=v),
//                     bx = (u&127)&15 (M/128), by = (u&127)>>4 (N/64).
//                     kp (z==1) stored TRANSPOSED [h][dh][s_att].
//   units [384,1408): small: rowblk = (u-384)&255, combo = (u-384)>>8.
// LDS union: proj 25600 B (As[32][132]+Wt[32][68]), small 21504 B.
// CLOSED (R10): LDS-staging p1 in the small path REGRESSES (-10 us): its
// global reads are wave-broadcast L2 hits already hidden by ~7 co-resident
// blocks; staging added 16 serializing barriers + 2-LDS-read-per-FMA.
// ---------------------------------------------------------------------------
__global__ __launch_bounds__(256) void k_prep(
    const float* __restrict__ q, const float* __restrict__ k, const float* __restrict__ v,
    const float* __restrict__ wq, const float* __restrict__ bq,
    const float* __restrict__ wk, const float* __restrict__ bk,
    const float* __restrict__ wv, const float* __restrict__ bv,
    const float* __restrict__ pq1, const float* __restrict__ pq2,
    const float* __restrict__ pk1, const float* __restrict__ pk2,
    const float* __restrict__ pqg, const float* __restrict__ pkg,
    const float* __restrict__ oq1, const float* __restrict__ oq2,
    const float* __restrict__ ok1, const float* __restrict__ ok2,
    const float* __restrict__ oqg, const float* __restrict__ okg,
    float* __restrict__ ws)
{
    __shared__ __align__(16) float smem[6400];   // 25600 B union

    const int u = blockIdx.x;
    const int tid = threadIdx.x;

    if (u < 384) {
        // ================= proj path: 128x64 tile =================
        float (*As)[132] = reinterpret_cast<float (*)[132]>(smem);         // [32][132]
        float (*Wt)[68]  = reinterpret_cast<float (*)[68]>(smem + 4224);   // [32][68]

        const int z = u >> 7;
        const int rest = u & 127;
        const int bx = rest & 15;
        const int by = rest >> 4;

        const float* A  = (z == 0) ? q  : (z == 1) ? k  : v;
        const float* W  = (z == 0) ? wq : (z == 1) ? wk : wv;
        const float* bs = (z == 0) ? bq : (z == 1) ? bk : bv;
        float* C = ws + (unsigned)z * 1048576u;

        const int tx = tid & 15, ty = tid >> 4;
        const int row0 = bx * 128;
        const int col0 = by * 64;

        float4 acc[8];
        #pragma unroll
        for (int i = 0; i < 8; ++i) acc[i] = make_float4(0.f, 0.f, 0.f, 0.f);

        for (int k0 = 0; k0 < DD; k0 += 32) {
            #pragma unroll
            for (int p = 0; p < 4; ++p) {
                int qi = tid + p * 256;            // 0..1023 quad index
                int row = qi >> 3;                 // 0..127
                int kk4 = (qi & 7) << 2;           // 0..28
                float4 a = *(const float4*)&A[(size_t)(row0 + row) * DD + k0 + kk4];
                As[kk4 + 0][row] = a.x;
                As[kk4 + 1][row] = a.y;
                As[kk4 + 2][row] = a.z;
                As[kk4 + 3][row] = a.w;
            }
            #pragma unroll
            for (int p = 0; p < 2; ++p) {
                int qi = tid + p * 256;
                int kk = qi >> 4;                  // 0..31
                int c4 = (qi & 15) << 2;           // 0..60
                *(float4*)&Wt[kk][c4] = *(const float4*)&W[(size_t)(k0 + kk) * DD + col0 + c4];
            }
            __syncthreads();
            #pragma unroll
            for (int kk = 0; kk < 32; ++kk) {
                float4 a0 = *(const float4*)&As[kk][ty << 3];
                float4 a1 = *(const float4*)&As[kk][(ty << 3) + 4];
                float4 w  = *(const float4*)&Wt[kk][tx << 2];
                acc[0].x += a0.x*w.x; acc[0].y += a0.x*w.y; acc[0].z += a0.x*w.z; acc[0].w += a0.x*w.w;
                acc[1].x += a0.y*w.x; acc[1].y += a0.y*w.y; acc[1].z += a0.y*w.z; acc[1].w += a0.y*w.w;
                acc[2].x += a0.z*w.x; acc[2].y += a0.z*w.y; acc[2].z += a0.z*w.z; acc[2].w += a0.z*w.w;
                acc[3].x += a0.w*w.x; acc[3].y += a0.w*w.y; acc[3].z += a0.w*w.z; acc[3].w += a0.w*w.w;
                acc[4].x += a1.x*w.x; acc[4].y += a1.x*w.y; acc[4].z += a1.x*w.z; acc[4].w += a1.x*w.w;
                acc[5].x += a1.y*w.x; acc[5].y += a1.y*w.y; acc[5].z += a1.y*w.z; acc[5].w += a1.y*w.w;
                acc[6].x += a1.z*w.x; acc[6].y += a1.z*w.y; acc[6].z += a1.z*w.z; acc[6].w += a1.z*w.w;
                acc[7].x += a1.w*w.x; acc[7].y += a1.w*w.y; acc[7].z += a1.w*w.z; acc[7].w += a1.w*w.w;
            }
            __syncthreads();
        }
        float4 bias4 = *(const float4*)&bs[col0 + (tx << 2)];

        if (z == 1) {
            // transposed store: flat o = s_in*512 + col -> (h = s_in>>7,
            // s_att = ((s_in&127)<<3)|(col>>6), dh = col&63).
            #pragma unroll
            for (int i = 0; i < 8; ++i) {
                const int row  = row0 + (ty << 3) + i;       // 0..2047
                const int bi   = row >> 10;
                const int s_in = row & 1023;
                const int h    = s_in >> 7;
                float va[4] = { acc[i].x + bias4.x, acc[i].y + bias4.y,
                                acc[i].z + bias4.z, acc[i].w + bias4.w };
                #pragma unroll
                for (int j = 0; j < 4; ++j) {
                    const int col   = col0 + (tx << 2) + j;
                    const int s_att = ((s_in & 127) << 3) | (col >> 6);
                    const int dh    = col & 63;
                    C[(size_t)bi * 524288u + (size_t)(((h << 6) + dh) << 10) + s_att] = va[j];
                }
            }
        } else {
            #pragma unroll
            for (int i = 0; i < 8; ++i) {
                float4 r;
                r.x = acc[i].x + bias4.x; r.y = acc[i].y + bias4.y;
                r.z = acc[i].z + bias4.z; r.w = acc[i].w + bias4.w;
                *(float4*)&C[(size_t)(row0 + (ty << 3) + i) * DD + col0 + (tx << 2)] = r;
            }
        }
    } else {
        // ================= small path (original, R9-proven) =================
        float (*qs)[512] = reinterpret_cast<float (*)[512]>(smem);        // [8][512]
        float (*u1s)[32] = reinterpret_cast<float (*)[32]>(smem + 4096);  // [8][32]
        float* p2s = smem + 4352;                                         // [1024]

        const int u2 = u - 384;
        const int rowblk = u2 & 255;
        const int combo = u2 >> 8;

        const float* A; const float* p1; const float* p2; const float* pg;
        float* dwout; float* gout;
        if (combo == 0)      { A = q; p1 = pq1; p2 = pq2; pg = pqg; dwout = ws + DWQ_PRE_OFF;  gout = ws + GQ_PRE_OFF;  }
        else if (combo == 1) { A = k; p1 = pk1; p2 = pk2; pg = pkg; dwout = ws + DWK_PRE_OFF;  gout = ws + GK_PRE_OFF;  }
        else if (combo == 2) { A = q; p1 = oq1; p2 = oq2; pg = oqg; dwout = ws + DWQ_POST_OFF; gout = ws + GQ_POST_OFF; }
        else                 { A = k; p1 = ok1; p2 = ok2; pg = okg; dwout = ws + DWK_POST_OFF; gout = ws + GK_POST_OFF; }

        const int row0 = rowblk * 8;

        for (int i = tid; i < 8 * 512; i += 256)
            qs[i >> 9][i & 511] = A[(size_t)(row0 + (i >> 9)) * 512 + (i & 511)];
        for (int i = tid; i < 1024; i += 256) p2s[i] = p2[i];
        __syncthreads();

        const int r = tid >> 5, c = tid & 31;
        float acc = 0.f;
        for (int d = 0; d < 512; ++d) acc += qs[r][d] * p1[d * 32 + c];
        float uu = 0.5f * acc * (1.f + erff(acc * 0.70710678118f));   // exact gelu
        u1s[r][c] = uu;
        __syncthreads();

        float dw = 0.f;
        #pragma unroll
        for (int cc = 0; cc < 32; ++cc) dw += u1s[r][cc] * p2s[cc * 32 + c];
        dwout[(size_t)(row0 + r) * 32 + c] = dw;

        if (c < 8) {
            float g = 0.f;
            for (int d = 0; d < 512; ++d) g += qs[r][d] * pg[d * 8 + c];
            gout[(size_t)(row0 + r) * 8 + c] = tanhf(g);
        }
    }
}

// ---------------------------------------------------------------------------
// K2: fused logits -> uncomposed -> pre -> probs -> post -> out
// FROZEN at R9 state (165.5 us, VGPR 60, no spill; bar_lds store-drain
// overlap). one block per (b, 4 t-rows); 1024 threads (16 waves, 4 w/SIMD).
// CLOSED AXES (do not retry):
//  - TB=2 pure (R7): dur 241 us; per-block fixed costs double. TB=4 wins.
//  - wmaxs fold / reshaped row_stats (R2-R5): ~1-2 GB scratch spill.
//  - launch_bounds 2nd arg must stay 4 (64-VGPR budget; 8 caps at 32).
//  - P3/P5 must stay in LOOP form (straight-line ss=tid spills, R3/R4).
// ---------------------------------------------------------------------------
__device__ __forceinline__ void row_stats(const float* Lb, float* rowm, float* rowsum, int tid)
{
    const int g = tid >> 5, l = tid & 31;          // 32 groups x 32 lanes
    const float* row = Lb + (g << 10);
    float m = -1e30f;
    #pragma unroll
    for (int i = 0; i < 8; ++i) {
        float4 v = *(const float4*)&row[(i << 7) + (l << 2)];
        m = fmaxf(m, fmaxf(fmaxf(v.x, v.y), fmaxf(v.z, v.w)));
    }
    #pragma unroll
    for (int o = 16; o >= 1; o >>= 1) m = fmaxf(m, __shfl_xor(m, o));
    float sm = 0.f;
    #pragma unroll
    for (int i = 0; i < 8; ++i) {
        float4 v = *(const float4*)&row[(i << 7) + (l << 2)];
        sm += __expf(v.x - m) + __expf(v.y - m) + __expf(v.z - m) + __expf(v.w - m);
    }
    #pragma unroll
    for (int o = 16; o >= 1; o >>= 1) sm += __shfl_xor(sm, o);
    if (l == 0) { rowm[g] = m; rowsum[g] = 1.0f / sm; }
}

__global__ __launch_bounds__(1024, 4) void k_fused(
    const float* __restrict__ ws, float* __restrict__ dout)
{
    __shared__ float Lb[TB * HH * 1024];     // 128 KB: logits->pre->probs->post
    __shared__ float qv[HH * TB * DH];       // 8 KB: q head-rows [h][t][d]; reused as P6 partials
    __shared__ float dqp[TB][32];
    __shared__ float dqo[TB][32];
    __shared__ float gqp_s[TB][8];
    __shared__ float gqo_s[TB][8];
    __shared__ float rowm[32];
    __shared__ float rowsum[32];             // holds RECIPROCAL of softmax denom

    const int tid = threadIdx.x;
    const int bid = blockIdx.x;
    const int b = bid & 1;                   // batch per XCD parity (L2 locality)
    const int t0 = (bid >> 1) * TB;

    const float* qp = ws + QP_OFF + b * 524288u;
    const float* kp = ws + KP_OFF + b * 524288u;   // TRANSPOSED: [h][dh][s]
    const float* vp = ws + VP_OFF + b * 524288u;
    const float* dwk_pre  = ws + DWK_PRE_OFF  + b * 32768u;
    const float* gk_pre   = ws + GK_PRE_OFF   + b * 8192u;
    const float* dwk_post = ws + DWK_POST_OFF + b * 32768u;
    const float* gk_post  = ws + GK_POST_OFF  + b * 8192u;
    const float* dwq_pre  = ws + DWQ_PRE_OFF  + b * 32768u;
    const float* gq_pre   = ws + GQ_PRE_OFF   + b * 8192u;
    const float* dwq_post = ws + DWQ_POST_OFF + b * 32768u;
    const float* gq_post  = ws + GQ_POST_OFF  + b * 8192u;

    // ---- P0: load q rows + per-t params ----
    for (int i = tid; i < HH * TB * DH; i += NB) {
        int hh = i >> 8, t = (i >> 6) & 3, d = i & 63;
        qv[i] = qp[(size_t)((hh << 10) + t0 + t) * 64 + d];
    }
    if (tid < TB * 32) {
        int t = tid >> 5, j = tid & 31;
        dqp[t][j] = dwq_pre[(t0 + t) * 32 + j];
        dqo[t][j] = dwq_post[(t0 + t) * 32 + j];
    }
    if (tid < TB * 8) {
        int t = tid >> 3, h2 = tid & 7;
        gqp_s[t][h2] = gq_pre[(t0 + t) * 8 + h2];
        gqo_s[t][h2] = gq_post[(t0 + t) * 8 + h2];
    }
    __syncthreads();

    // ---- P1: logits = (qh . kh)/8 ; wave -> (head, s-half); kp is [h][d][s]
    //      lane covers 4 consecutive s (x2 chunks of 256) -> fully coalesced ----
    {
        const int w = tid >> 6, lane = tid & 63;
        const int h = w & 7;
        const int sb = (w >> 3) << 9;                 // 0 or 512
        const float* kbase = kp + ((size_t)(h << 6) << 10) + sb + (lane << 2);

        float4 acc0[TB], acc1[TB];
        #pragma unroll
        for (int t = 0; t < TB; ++t) {
            acc0[t] = make_float4(0.f, 0.f, 0.f, 0.f);
            acc1[t] = make_float4(0.f, 0.f, 0.f, 0.f);
        }
        for (int d0 = 0; d0 < 64; d0 += 4) {
            float4 qq[TB];
            #pragma unroll
            for (int t = 0; t < TB; ++t)
                qq[t] = *(const float4*)&qv[((h << 2 | t) << 6) + d0];
            #pragma unroll
            for (int dd = 0; dd < 4; ++dd) {
                const float* kr = kbase + ((size_t)(d0 + dd) << 10);
                float4 k0 = *(const float4*)kr;          // s = sb + lane*4
                float4 k1 = *(const float4*)(kr + 256);  // s = sb + 256 + lane*4
                #pragma unroll
                for (int t = 0; t < TB; ++t) {
                    float qd = (dd == 0) ? qq[t].x : (dd == 1) ? qq[t].y
                             : (dd == 2) ? qq[t].z : qq[t].w;
                    acc0[t].x += qd * k0.x; acc0[t].y += qd * k0.y;
                    acc0[t].z += qd * k0.z; acc0[t].w += qd * k0.w;
                    acc1[t].x += qd * k1.x; acc1[t].y += qd * k1.y;
                    acc1[t].z += qd * k1.z; acc1[t].w += qd * k1.w;
                }
            }
        }
        #pragma unroll
        for (int t = 0; t < TB; ++t) {
            float4 r0, r1;
            r0.x = acc0[t].x * 0.125f; r0.y = acc0[t].y * 0.125f;
            r0.z = acc0[t].z * 0.125f; r0.w = acc0[t].w * 0.125f;
            r1.x = acc1[t].x * 0.125f; r1.y = acc1[t].y * 0.125f;
            r1.z = acc1[t].z * 0.125f; r1.w = acc1[t].w * 0.125f;
            *(float4*)&Lb[((t << 3 | h) << 10) + sb + (lane << 2)] = r0;
            *(float4*)&Lb[((t << 3 | h) << 10) + sb + 256 + (lane << 2)] = r1;
        }
    }
    __syncthreads();

    // ---- P2: row stats of logits ----
    row_stats(Lb, rowm, rowsum, tid);
    __syncthreads();

    // ---- P3: write uncomposed; pre-compose in place ----
    for (int ss = tid; ss < 1024; ss += NB) {
        float kd[32], gk8[8];
        {
            const float4* p = (const float4*)&dwk_pre[ss << 5];
            #pragma unroll
            for (int j = 0; j < 8; ++j) *(float4*)&kd[j << 2] = p[j];
            const float4* g = (const float4*)&gk_pre[ss << 3];
            *(float4*)&gk8[0] = g[0];
            *(float4*)&gk8[4] = g[1];
        }
        #pragma unroll
        for (int t = 0; t < TB; ++t) {
            float L[8];
            #pragma unroll
            for (int h = 0; h < 8; ++h) L[h] = Lb[((t << 3 | h) << 10) + ss];
            #pragma unroll
            for (int h = 0; h < 8; ++h) {
                int r = (t << 3) | h;
                float e = __expf(L[h] - rowm[r]) * rowsum[r];
                __builtin_nontemporal_store(e,
                    &dout[UNC_OFF + (unsigned)(((b << 3 | h) << 10) + t0 + t) * 1024u + ss]);
            }
            float hq0 = 0.f, hq1 = 0.f, hk0 = 0.f, hk1 = 0.f;
            #pragma unroll
            for (int h = 0; h < 8; ++h) {
                hq0 += L[h] * dqp[t][h];
                hq1 += L[h] * dqp[t][8 + h];
                hk0 += L[h] * kd[h];
                hk1 += L[h] * kd[8 + h];
            }
            #pragma unroll
            for (int h = 0; h < 8; ++h) {
                float pre = L[h]
                          + hq0 * dqp[t][16 + h] + hq1 * dqp[t][24 + h]
                          + hk0 * kd[16 + h]     + hk1 * kd[24 + h]
                          + L[h] * gqp_s[t][h]   + L[h] * gk8[h];
                Lb[((t << 3 | h) << 10) + ss] = pre;
            }
        }
    }
    bar_lds();   // unc stores keep draining under P4

    // ---- P4: row stats of pre ----
    row_stats(Lb, rowm, rowsum, tid);
    __syncthreads();

    // ---- P5: write probs; post-compose in place; write post ----
    for (int ss = tid; ss < 1024; ss += NB) {
        float kd[32], gk8[8];
        {
            const float4* p = (const float4*)&dwk_post[ss << 5];
            #pragma unroll
            for (int j = 0; j < 8; ++j) *(float4*)&kd[j << 2] = p[j];
            const float4* g = (const float4*)&gk_post[ss << 3];
            *(float4*)&gk8[0] = g[0];
            *(float4*)&gk8[4] = g[1];
        }
        #pragma unroll
        for (int t = 0; t < TB; ++t) {
            float P[8];
            #pragma unroll
            for (int h = 0; h < 8; ++h) {
                int r = (t << 3) | h;
                P[h] = __expf(Lb[((t << 3 | h) << 10) + ss] - rowm[r]) * rowsum[r];
                __builtin_nontemporal_store(P[h],
                    &dout[PROBS_OFF + (unsigned)(((b << 3 | h) << 10) + t0 + t) * 1024u + ss]);
            }
            float hq0 = 0.f, hq1 = 0.f, hk0 = 0.f, hk1 = 0.f;
            #pragma unroll
            for (int h = 0; h < 8; ++h) {
                hq0 += P[h] * dqo[t][h];
                hq1 += P[h] * dqo[t][8 + h];
                hk0 += P[h] * kd[h];
                hk1 += P[h] * kd[8 + h];
            }
            #pragma unroll
            for (int h = 0; h < 8; ++h) {
                float pst = P[h]
                          + hq0 * dqo[t][16 + h] + hq1 * dqo[t][24 + h]
                          + hk0 * kd[16 + h]     + hk1 * kd[24 + h]
                          + P[h] * gqo_s[t][h]   + P[h] * gk8[h];
                Lb[((t << 3 | h) << 10) + ss] = pst;
                __builtin_nontemporal_store(pst,
                    &dout[POST_OFF + (unsigned)(((b << 3 | h) << 10) + t0 + t) * 1024u + ss]);
            }
        }
    }
    bar_lds();   // probs/post stores keep draining under P6

    // ---- P6: out = post @ v ; wave -> (head, s-half); float4 LDS reads ----
    {
        const int w = tid >> 6, lane = tid & 63;
        const int h = w & 7;
        const int shalf = w >> 3;                 // 0/1: s-half
        const int dq = lane & 15, sq = lane >> 4; // dq: out col quad, sq: s sub-quad
        float4 acc[TB];
        #pragma unroll
        for (int t = 0; t < TB; ++t) acc[t] = make_float4(0.f, 0.f, 0.f, 0.f);

        const int sbase = (shalf << 9) + (sq << 2);
        #pragma unroll 2
        for (int si = 0; si < 32; ++si) {
            const int s0 = sbase + (si << 4);
            float4 p4[TB];
            #pragma unroll
            for (int t = 0; t < TB; ++t)
                p4[t] = *(const float4*)&Lb[((t << 3 | h) << 10) + s0];
            #pragma unroll
            for (int j = 0; j < 4; ++j) {
                float4 vv = *(const float4*)&vp[((size_t)((h << 10) + s0 + j) << 6) + (dq << 2)];
                #pragma unroll
                for (int t = 0; t < TB; ++t) {
                    float pc = (j == 0) ? p4[t].x : (j == 1) ? p4[t].y
                             : (j == 2) ? p4[t].z : p4[t].w;
                    acc[t].x += pc * vv.x; acc[t].y += pc * vv.y;
                    acc[t].z += pc * vv.z; acc[t].w += pc * vv.w;
                }
            }
        }
        #pragma unroll
        for (int t = 0; t < TB; ++t) {
            #pragma unroll
            for (int o = 16; o <= 32; o <<= 1) {
                acc[t].x += __shfl_xor(acc[t].x, o);
                acc[t].y += __shfl_xor(acc[t].y, o);
                acc[t].z += __shfl_xor(acc[t].z, o);
                acc[t].w += __shfl_xor(acc[t].w, o);
            }
        }
        // cross-wave combine of the two s-halves via qv (dead after P1)
        if (shalf == 1 && sq == 0) {
            #pragma unroll
            for (int t = 0; t < TB; ++t)
                *(float4*)&qv[((h << 2 | t) << 6) + (dq << 2)] = acc[t];
        }
        bar_lds();   // only qv (LDS) ordering needed here
        if (shalf == 0 && sq == 0) {
            #pragma unroll
            for (int t = 0; t < TB; ++t) {
                float4 pr = *(const float4*)&qv[((h << 2 | t) << 6) + (dq << 2)];
                float4 r;
                r.x = acc[t].x + pr.x; r.y = acc[t].y + pr.y;
                r.z = acc[t].z + pr.z; r.w = acc[t].w + pr.w;
                *(float4*)&dout[OUT_OFF + (unsigned)((b << 10) + t0 + t) * 512u + (h << 6) + (dq << 2)] = r;
            }
        }
    }
}

// ---------------------------------------------------------------------------
extern "C" void kernel_launch(void* const* d_in, const int* in_sizes, int n_in,
                              void* d_out, int out_size, void* d_ws, size_t ws_size,
                              hipStream_t stream) {
    (void)in_sizes; (void)n_in; (void)out_size; (void)ws_size;
    const float* query = (const float*)d_in[0];
    const float* key   = (const float*)d_in[1];
    const float* value = (const float*)d_in[2];
    const float* wq = (const float*)d_in[3];
    const float* bq = (const float*)d_in[4];
    const float* wk = (const float*)d_in[5];
    const float* bk = (const float*)d_in[6];
    const float* wv = (const float*)d_in[7];
    const float* bv = (const float*)d_in[8];
    const float* pre_q1 = (const float*)d_in[9];
    const float* pre_q2 = (const float*)d_in[10];
    const float* pre_k1 = (const float*)d_in[11];
    const float* pre_k2 = (const float*)d_in[12];
    const float* pre_qg = (const float*)d_in[13];
    const float* pre_kg = (const float*)d_in[14];
    const float* post_q1 = (const float*)d_in[15];
    const float* post_q2 = (const float*)d_in[16];
    const float* post_k1 = (const float*)d_in[17];
    const float* post_k2 = (const float*)d_in[18];
    const float* post_qg = (const float*)d_in[19];
    const float* post_kg = (const float*)d_in[20];

    float* ws = (float*)d_ws;
    float* out = (float*)d_out;

    k_prep<<<1408, 256, 0, stream>>>(query, key, value, wq, bq, wk, bk, wv, bv,
        pre_q1, pre_q2, pre_k1, pre_k2, pre_qg, pre_kg,
        post_q1, post_q2, post_k1, post_k2, post_qg, post_kg, ws);
    k_fused<<<512, NB, 0, stream>>>(ws, out);
}